// Round 11
// baseline (14117.844 us; speedup 1.0000x reference)
//
#include <hip/hip_runtime.h>
#include <math.h>

#define N_NODES   50000
#define N_EDGES   800000
#define IN_DIM    128
#define HIDDEN    256
#define N_ETYPES  13
#define N_STEPS   6
#define NUM_GRAPHS 64
#define NKEYS     (N_ETYPES * N_NODES)
#define SCAN_T    512

typedef __attribute__((ext_vector_type(8))) short bf16x8;
typedef __attribute__((ext_vector_type(4))) float f32x4;
typedef __attribute__((ext_vector_type(4))) unsigned short u16x4;
typedef __attribute__((ext_vector_type(8))) _Float16 f16x8;
typedef __attribute__((ext_vector_type(4))) _Float16 f16x4;

__device__ __forceinline__ float bf2f(unsigned short u) {
    return __uint_as_float((unsigned)u << 16);
}
__device__ __forceinline__ void fsplit(float x, unsigned short& hi, unsigned short& lo) {
    unsigned u = __float_as_uint(x);
    hi = (unsigned short)(u >> 16);
    float l = x - __uint_as_float((u >> 16) << 16);
    lo = (unsigned short)(__float_as_uint(l) >> 16);
}

// ---------------- init h0 = [feat | zeros]: bf16 hi/lo pair + f16 shadow ---
__global__ __launch_bounds__(256) void k_init_h(const float* __restrict__ feat,
                                                unsigned short* __restrict__ hHi,
                                                unsigned short* __restrict__ hLo,
                                                _Float16* __restrict__ hF16) {
    int i = blockIdx.x * 256 + threadIdx.x;          // float4 index over N*64
    if (i >= N_NODES * 64) return;
    int v = i >> 6;
    int q = i & 63;
    float4 val;
    if (q < 32) val = ((const float4*)(feat + (size_t)v * IN_DIM))[q];
    else        val = make_float4(0.f, 0.f, 0.f, 0.f);
    // fsplit cannot bind references to ext_vector elements (clang): scalars first.
    unsigned short h0, l0, h1, l1, h2, l2, h3, l3;
    fsplit(val.x, h0, l0);
    fsplit(val.y, h1, l1);
    fsplit(val.z, h2, l2);
    fsplit(val.w, h3, l3);
    u16x4 hi4, lo4;
    hi4[0] = h0; hi4[1] = h1; hi4[2] = h2; hi4[3] = h3;
    lo4[0] = l0; lo4[1] = l1; lo4[2] = l2; lo4[3] = l3;
    *(u16x4*)(hHi + (size_t)v * 256 + q * 4) = hi4;
    *(u16x4*)(hLo + (size_t)v * 256 + q * 4) = lo4;
    f16x4 f4;
    f4[0] = (_Float16)val.x; f4[1] = (_Float16)val.y;
    f4[2] = (_Float16)val.z; f4[3] = (_Float16)val.w;
    *(f16x4*)(hF16 + (size_t)v * 256 + q * 4) = f4;
}

// ---------------- split W (message) into bf16 hi/lo, transposed to [t][n][k]
__global__ __launch_bounds__(256) void k_splitW(const float* __restrict__ W,
                                                short* __restrict__ Whi,
                                                short* __restrict__ Wlo) {
    int i = blockIdx.x * 256 + threadIdx.x;          // over 13*256*256
    if (i >= N_ETYPES * 65536) return;
    int t = i >> 16, rem = i & 65535, n = rem >> 8, k = rem & 255;
    float x = W[(size_t)t * 65536 + k * 256 + n];    // W is [t][k][n]
    unsigned short hb, lb;
    fsplit(x, hb, lb);
    Whi[i] = (short)hb;                              // i == t*65536 + n*256 + k
    Wlo[i] = (short)lb;
}

// ---------------- split a linear weight [768][256] elementwise -------------
__global__ __launch_bounds__(256) void k_splitLin(const float* __restrict__ Wsrc,
                                                  short* __restrict__ hi,
                                                  short* __restrict__ lo, int n) {
    int i = blockIdx.x * 256 + threadIdx.x;
    if (i >= n) return;
    unsigned short hb, lb;
    fsplit(Wsrc[i], hb, lb);
    hi[i] = (short)hb;
    lo[i] = (short)lb;
}

// ---------------- CSR build: histogram / scan / place ----------------
__global__ __launch_bounds__(256) void k_hist(const int* __restrict__ dst,
                                              const int* __restrict__ et,
                                              int* __restrict__ counts) {
    int e = blockIdx.x * 256 + threadIdx.x;
    if (e >= N_EDGES) return;
    int key = et[e] * N_NODES + dst[e];
    atomicAdd(&counts[key], 1);
}

__global__ __launch_bounds__(SCAN_T) void k_scan1(const int* __restrict__ in,
                                                  int* __restrict__ lexcl,
                                                  int* __restrict__ bsums, int n) {
    __shared__ int s[SCAN_T];
    int i = blockIdx.x * SCAN_T + threadIdx.x;
    int v = (i < n) ? in[i] : 0;
    s[threadIdx.x] = v;
    __syncthreads();
    for (int off = 1; off < SCAN_T; off <<= 1) {
        int t = (threadIdx.x >= off) ? s[threadIdx.x - off] : 0;
        __syncthreads();
        s[threadIdx.x] += t;
        __syncthreads();
    }
    if (i < n) lexcl[i] = s[threadIdx.x] - v;
    if (threadIdx.x == SCAN_T - 1) bsums[blockIdx.x] = s[SCAN_T - 1];
}

__global__ __launch_bounds__(256) void k_scan2(int* __restrict__ bsums, int nb,
                                               int* __restrict__ ptr) {
    __shared__ int s[256];
    int tid = threadIdx.x;
    const int C = (nb + 255) / 256;                  // <= 8
    int vals[8];
    int base = tid * C;
    int sum = 0;
    for (int i = 0; i < C; ++i) {
        int idx = base + i;
        int v = (idx < nb) ? bsums[idx] : 0;
        vals[i] = sum;
        sum += v;
    }
    s[tid] = sum;
    __syncthreads();
    int own = sum;
    for (int off = 1; off < 256; off <<= 1) {
        int t = (tid >= off) ? s[tid - off] : 0;
        __syncthreads();
        s[tid] += t;
        __syncthreads();
    }
    int exclBlk = s[tid] - own;
    for (int i = 0; i < C; ++i) {
        int idx = base + i;
        if (idx < nb) bsums[idx] = exclBlk + vals[i];
    }
    if (tid == 0) ptr[NKEYS] = N_EDGES;              // end sentinel
}

__global__ __launch_bounds__(SCAN_T) void k_scan3(const int* __restrict__ lexcl,
                                                  const int* __restrict__ bsums,
                                                  int* __restrict__ ptr, int n) {
    int i = blockIdx.x * SCAN_T + threadIdx.x;
    if (i < n) ptr[i] = lexcl[i] + bsums[blockIdx.x];
}

// ebuf[pos] packs (dst<<16)|src (both < 65536); unsigned arithmetic.
__global__ __launch_bounds__(256) void k_place(const int* __restrict__ dst,
                                               const int* __restrict__ et,
                                               const int* __restrict__ src,
                                               int* __restrict__ cursor,
                                               unsigned* __restrict__ ebuf) {
    int e = blockIdx.x * 256 + threadIdx.x;
    if (e >= N_EDGES) return;
    int d = dst[e];
    int key = et[e] * N_NODES + d;
    int pos = atomicAdd(&cursor[key], 1);
    ebuf[pos] = ((unsigned)d << 16) | (unsigned)src[e];
}

// ---------------- fused message kernel: f16 gather + MFMA ------------------
// R10 post-mortem: hi-only bf16 gather (2^-8, biased truncation) missed the
// accuracy threshold by 1.9x. Gather now reads an f16 shadow copy (2^-11,
// unbiased RNE): same 512B/row, >=16x less error.
__device__ __forceinline__ void split8(const float4& A, const float4& B,
                                       bf16x8& hi, bf16x8& lo) {
    float x[8] = {A.x, A.y, A.z, A.w, B.x, B.y, B.z, B.w};
    #pragma unroll
    for (int e = 0; e < 8; ++e) {
        unsigned short hb, lb;
        fsplit(x[e], hb, lb);
        hi[e] = (short)hb;
        lo[e] = (short)lb;
    }
}

__global__ __launch_bounds__(256, 4) void k_msg(const unsigned* __restrict__ ebuf,
                                                const int* __restrict__ ptr,
                                                const _Float16* __restrict__ hF16,
                                                const short* __restrict__ Whi,
                                                const short* __restrict__ Wlo,
                                                float* __restrict__ a) {
    __shared__ float4 Sh4[32 * 64];                  // 32 rows x 256 f32, 32 KB
    const int br   = blockIdx.x * 32;
    const int tid  = threadIdx.x;
    const int l    = tid & 63;
    const int w    = tid >> 6;                       // wave: cols [64w, 64w+64)
    const int ln15 = l & 15;
    const int lhi  = l >> 4;                         // 0..3
    const int g    = tid >> 4;                       // gather group 0..15
    const int q    = tid & 15;                       // lane in group
    float* shf = (float*)Sh4;

    f32x4 acc[2][4] = {};                            // [row-frag][col-frag]

    for (int t = 0; t < N_ETYPES; ++t) {
        // ---- zero Sh (2048 float4 / 256 threads = 8 each)
        float4 z4 = make_float4(0.f, 0.f, 0.f, 0.f);
        #pragma unroll
        for (int i = 0; i < 8; ++i) Sh4[tid + i * 256] = z4;
        __syncthreads();
        // ---- edge-parallel gather (f16 rows, 2x16B loads per lane)
        {
            int base = t * N_NODES + br;
            int endk = (br + 32 <= N_NODES) ? (base + 32) : (t * N_NODES + N_NODES);
            int beg  = ptr[base];
            int end  = ptr[endk];
            for (int i = beg + g; i < end; i += 16) {
                unsigned pk = ebuf[i];
                int s = (int)(pk & 0xFFFFu);
                int r = (int)(pk >> 16) - br;        // 0..31 by construction
                int sw = r & 7;
                #pragma unroll
                for (int j2 = 0; j2 < 2; ++j2) {
                    const _Float16* vp = hF16 + (size_t)s * 256 + j2 * 128 + q * 8;
                    f16x8 v8 = *reinterpret_cast<const f16x8*>(vp);
                    int c0 = (j2 * 32 + 2 * q) ^ sw;     // swizzled float4 cols
                    int c1 = (j2 * 32 + 2 * q + 1) ^ sw;
                    float* p0 = shf + ((r * 64 + c0) << 2);
                    float* p1 = shf + ((r * 64 + c1) << 2);
                    atomicAdd(p0 + 0, (float)v8[0]);
                    atomicAdd(p0 + 1, (float)v8[1]);
                    atomicAdd(p0 + 2, (float)v8[2]);
                    atomicAdd(p0 + 3, (float)v8[3]);
                    atomicAdd(p1 + 0, (float)v8[4]);
                    atomicAdd(p1 + 1, (float)v8[5]);
                    atomicAdd(p1 + 2, (float)v8[6]);
                    atomicAdd(p1 + 3, (float)v8[7]);
                }
            }
        }
        __syncthreads();
        // ---- split-bf16 MFMA GEMM: acc += Sh @ W[t][:, 64w..64w+64)
        const short* WH = Whi + ((size_t)t << 16);
        const short* WL = Wlo + ((size_t)t << 16);
        #pragma unroll 2
        for (int K0 = 0; K0 < 8; ++K0) {             // K = K0*32
            bf16x8 bh[4], bl[4];
            #pragma unroll
            for (int cb = 0; cb < 4; ++cb) {
                int col = (w << 6) + (cb << 4) + ln15;
                size_t off = (size_t)col * 256 + (K0 << 5) + (lhi << 3);
                bh[cb] = *reinterpret_cast<const bf16x8*>(WH + off);
                bl[cb] = *reinterpret_cast<const bf16x8*>(WL + off);
            }
            #pragma unroll
            for (int rf = 0; rf < 2; ++rf) {
                int row = (rf << 4) + ln15;
                int j0  = (K0 << 3) + (lhi << 1);
                int sw  = row & 7;
                float4 a0 = Sh4[row * 64 + (j0 ^ sw)];
                float4 a1 = Sh4[row * 64 + ((j0 + 1) ^ sw)];
                bf16x8 ah, al;
                split8(a0, a1, ah, al);
                #pragma unroll
                for (int cb = 0; cb < 4; ++cb) {
                    acc[rf][cb] = __builtin_amdgcn_mfma_f32_16x16x32_bf16(ah, bh[cb], acc[rf][cb], 0, 0, 0);
                    acc[rf][cb] = __builtin_amdgcn_mfma_f32_16x16x32_bf16(ah, bl[cb], acc[rf][cb], 0, 0, 0);
                    acc[rf][cb] = __builtin_amdgcn_mfma_f32_16x16x32_bf16(al, bh[cb], acc[rf][cb], 0, 0, 0);
                }
            }
        }
        __syncthreads();                             // Sh reused next etype
    }
    // ---- C write: C/D layout col=lane&15, row=(lane>>4)*4+reg
    #pragma unroll
    for (int rf = 0; rf < 2; ++rf) {
        #pragma unroll
        for (int m = 0; m < 4; ++m) {
            int row = br + (rf << 4) + (lhi << 2) + m;
            if (row < N_NODES) {
                #pragma unroll
                for (int cb = 0; cb < 4; ++cb) {
                    int col = (w << 6) + (cb << 4) + ln15;
                    a[(size_t)row * 256 + col] = acc[rf][cb][m];
                }
            }
        }
    }
}

// ---------------- MFMA GRU kernel (h state = bf16 hi/lo; writes f16 shadow)
// Grid (4, 782): the 4 f0-blocks of one row-tile are dispatch-adjacent ->
// co-resident -> share a/h reads in L2. h hi/lo loads feed MFMA directly.
__device__ __forceinline__ float sigm(float x) { return 1.0f / (1.0f + expf(-x)); }

__global__ __launch_bounds__(256, 2) void k_gru(const float* __restrict__ a,
                                                const unsigned short* __restrict__ hHi,
                                                const unsigned short* __restrict__ hLo,
                                                const short* __restrict__ WihH,
                                                const short* __restrict__ WihL,
                                                const short* __restrict__ WhhH,
                                                const short* __restrict__ WhhL,
                                                const float* __restrict__ b_ih,
                                                const float* __restrict__ b_hh,
                                                unsigned short* __restrict__ hNHi,
                                                unsigned short* __restrict__ hNLo,
                                                _Float16* __restrict__ hNF16) {
    const int f0   = blockIdx.x * 64;                // x-fast: f0 varies first
    const int br   = blockIdx.y * 64;
    const int tid  = threadIdx.x;
    const int w    = tid >> 6;
    const int l    = tid & 63;
    const int ln15 = l & 15;
    const int lhi  = l >> 4;

    f32x4 accx[3][4] = {};                           // [gate][col-frag]
    f32x4 acch[3][4] = {};

    int rowA = br + (w << 4) + ln15;                 // A-frag row for this lane
    if (rowA >= N_NODES) rowA = N_NODES - 1;         // clamp, stores guarded
    const float* aRow = a + (size_t)rowA * 256;
    const unsigned short* hHiRow = hHi + (size_t)rowA * 256;
    const unsigned short* hLoRow = hLo + (size_t)rowA * 256;

    #pragma unroll 2
    for (int K0 = 0; K0 < 8; ++K0) {
        const int koff = (K0 << 5) + (lhi << 3);
        float4 av0 = *(const float4*)(aRow + koff);
        float4 av1 = *(const float4*)(aRow + koff + 4);
        bf16x8 aH, aL;
        split8(av0, av1, aH, aL);
        bf16x8 hH = *reinterpret_cast<const bf16x8*>(hHiRow + koff);
        bf16x8 hL = *reinterpret_cast<const bf16x8*>(hLoRow + koff);
        #pragma unroll
        for (int g = 0; g < 3; ++g) {
            #pragma unroll
            for (int cb = 0; cb < 4; ++cb) {
                int col = g * 256 + f0 + (cb << 4) + ln15;
                size_t off = (size_t)col * 256 + koff;
                bf16x8 bH = *reinterpret_cast<const bf16x8*>(WihH + off);
                bf16x8 bL = *reinterpret_cast<const bf16x8*>(WihL + off);
                accx[g][cb] = __builtin_amdgcn_mfma_f32_16x16x32_bf16(aH, bH, accx[g][cb], 0, 0, 0);
                accx[g][cb] = __builtin_amdgcn_mfma_f32_16x16x32_bf16(aH, bL, accx[g][cb], 0, 0, 0);
                accx[g][cb] = __builtin_amdgcn_mfma_f32_16x16x32_bf16(aL, bH, accx[g][cb], 0, 0, 0);
                bH = *reinterpret_cast<const bf16x8*>(WhhH + off);
                bL = *reinterpret_cast<const bf16x8*>(WhhL + off);
                acch[g][cb] = __builtin_amdgcn_mfma_f32_16x16x32_bf16(hH, bH, acch[g][cb], 0, 0, 0);
                acch[g][cb] = __builtin_amdgcn_mfma_f32_16x16x32_bf16(hH, bL, acch[g][cb], 0, 0, 0);
                acch[g][cb] = __builtin_amdgcn_mfma_f32_16x16x32_bf16(hL, bH, acch[g][cb], 0, 0, 0);
            }
        }
    }
    // ---- gate epilogue; C/D frag: col = 16cb+ln15, row = 16w + 4*lhi + m
    #pragma unroll
    for (int cb = 0; cb < 4; ++cb) {
        int f = f0 + (cb << 4) + ln15;
        float bxr = b_ih[f], bxz = b_ih[256 + f], bxn = b_ih[512 + f];
        float bhr = b_hh[f], bhz = b_hh[256 + f], bhn = b_hh[512 + f];
        #pragma unroll
        for (int m = 0; m < 4; ++m) {
            int row = br + (w << 4) + (lhi << 2) + m;
            if (row >= N_NODES) continue;
            size_t idx = (size_t)row * 256 + f;
            float hv = bf2f(hHi[idx]) + bf2f(hLo[idx]);
            float r = sigm(accx[0][cb][m] + bxr + acch[0][cb][m] + bhr);
            float z = sigm(accx[1][cb][m] + bxz + acch[1][cb][m] + bhz);
            float n = tanhf(accx[2][cb][m] + bxn + r * (acch[2][cb][m] + bhn));
            float o = (1.f - z) * n + z * hv;
            unsigned short ohi, olo;
            fsplit(o, ohi, olo);
            hNHi[idx] = ohi;
            hNLo[idx] = olo;
            hNF16[idx] = (_Float16)o;
        }
    }
}

// ---------------- readout ----------------
__global__ __launch_bounds__(256) void k_readout1(const unsigned short* __restrict__ hHi,
                                                  const unsigned short* __restrict__ hLo,
                                                  const int* __restrict__ gid,
                                                  float* __restrict__ hg) {
    int row0 = blockIdx.x * 32;
    if (row0 >= N_NODES) return;
    int f = threadIdx.x;
    int end = row0 + 32; if (end > N_NODES) end = N_NODES;
    float acc = 0.f;
    int cur = gid[row0];
    for (int r = row0; r < end; ++r) {
        int g = gid[r];
        if (g != cur) {
            atomicAdd(&hg[cur * HIDDEN + f], acc);
            acc = 0.f; cur = g;
        }
        size_t idx = (size_t)r * HIDDEN + f;
        float x = bf2f(hHi[idx]) + bf2f(hLo[idx]);
        acc += (x > 0.f) ? x : 0.f;
    }
    atomicAdd(&hg[cur * HIDDEN + f], acc);
}

__global__ __launch_bounds__(256) void k_readout2(const float* __restrict__ hg,
                                                  const float* __restrict__ Wc,
                                                  const float* __restrict__ bc,
                                                  float* __restrict__ out) {
    __shared__ float s[256];
    int g = blockIdx.x;
    int f = threadIdx.x;
    s[f] = hg[g * HIDDEN + f] * Wc[f];
    __syncthreads();
    for (int off = 128; off > 0; off >>= 1) {
        if (f < off) s[f] += s[f + off];
        __syncthreads();
    }
    if (f == 0) out[g] = 1.0f / (1.0f + expf(-(s[0] + bc[0])));
}

// ---------------- launch ----------------
extern "C" void kernel_launch(void* const* d_in, const int* in_sizes, int n_in,
                              void* d_out, int out_size, void* d_ws, size_t ws_size,
                              hipStream_t stream) {
    const float* feat  = (const float*)d_in[0];
    const float* W     = (const float*)d_in[1];
    const float* W_ih  = (const float*)d_in[2];
    const float* W_hh  = (const float*)d_in[3];
    const float* b_ih  = (const float*)d_in[4];
    const float* b_hh  = (const float*)d_in[5];
    const float* Wc    = (const float*)d_in[6];
    const float* bc    = (const float*)d_in[7];
    const int*   src   = (const int*)d_in[8];
    const int*   dst   = (const int*)d_in[9];
    const int*   etype = (const int*)d_in[10];
    const int*   gid   = (const int*)d_in[11];
    float* out = (float*)d_out;

    char* ws = (char*)d_ws;
    size_t off = 0;
    auto alloc = [&](size_t bytes) {
        void* p = ws + off;
        off += (bytes + 255) & ~(size_t)255;
        return p;
    };
    // total ~193 MB
    unsigned short* hHiA = (unsigned short*)alloc((size_t)N_NODES * HIDDEN * 2); // 25.6 MB
    unsigned short* hLoA = (unsigned short*)alloc((size_t)N_NODES * HIDDEN * 2);
    unsigned short* hHiB = (unsigned short*)alloc((size_t)N_NODES * HIDDEN * 2);
    unsigned short* hLoB = (unsigned short*)alloc((size_t)N_NODES * HIDDEN * 2);
    _Float16* hF16 = (_Float16*)alloc((size_t)N_NODES * HIDDEN * 2);             // 25.6 MB, single buffer
    float* a    = (float*)alloc((size_t)N_NODES * HIDDEN * 4);   // 51.2 MB
    int* bufA   = (int*)alloc((size_t)(NKEYS + 1) * 4);          // counts, then ptr
    int* bufB   = (int*)alloc((size_t)NKEYS * 4);                // lexcl, then cursor
    unsigned* ebuf = (unsigned*)alloc((size_t)N_EDGES * 4);      // (dst<<16)|src
    int* bsums  = (int*)alloc((size_t)2048 * 4);
    float* hg   = (float*)alloc((size_t)NUM_GRAPHS * HIDDEN * 4);
    short* Whi  = (short*)alloc((size_t)N_ETYPES * 65536 * 2);   // 1.7 MB
    short* Wlo  = (short*)alloc((size_t)N_ETYPES * 65536 * 2);   // 1.7 MB
    short* WihH = (short*)alloc((size_t)768 * 256 * 2);          // 393 KB
    short* WihL = (short*)alloc((size_t)768 * 256 * 2);
    short* WhhH = (short*)alloc((size_t)768 * 256 * 2);
    short* WhhL = (short*)alloc((size_t)768 * 256 * 2);
    (void)ws_size; (void)n_in; (void)in_sizes; (void)out_size;

    const int SCAN_BLOCKS = (NKEYS + SCAN_T - 1) / SCAN_T;       // 1270
    const int NLIN = 768 * 256;

    // ---- CSR build, bucketed by (etype, dst) ----
    hipMemsetAsync(bufA, 0, (size_t)NKEYS * 4, stream);
    k_hist<<<(N_EDGES + 255) / 256, 256, 0, stream>>>(dst, etype, bufA);
    k_scan1<<<SCAN_BLOCKS, SCAN_T, 0, stream>>>(bufA, bufB, bsums, NKEYS);
    k_scan2<<<1, 256, 0, stream>>>(bsums, SCAN_BLOCKS, bufA);
    k_scan3<<<SCAN_BLOCKS, SCAN_T, 0, stream>>>(bufB, bsums, bufA, NKEYS);
    hipMemcpyAsync(bufB, bufA, (size_t)NKEYS * 4, hipMemcpyDeviceToDevice, stream);
    k_place<<<(N_EDGES + 255) / 256, 256, 0, stream>>>(dst, etype, src, bufB, ebuf);

    // ---- weight splits (once) + h0 ----
    k_splitW<<<(N_ETYPES * 65536 + 255) / 256, 256, 0, stream>>>(W, Whi, Wlo);
    k_splitLin<<<(NLIN + 255) / 256, 256, 0, stream>>>(W_ih, WihH, WihL, NLIN);
    k_splitLin<<<(NLIN + 255) / 256, 256, 0, stream>>>(W_hh, WhhH, WhhL, NLIN);
    k_init_h<<<(N_NODES * 64 + 255) / 256, 256, 0, stream>>>(feat, hHiA, hLoA, hF16);

    unsigned short* hcHi = hHiA; unsigned short* hcLo = hLoA;
    unsigned short* hnHi = hHiB; unsigned short* hnLo = hLoB;
    const dim3 gMsg((N_NODES + 31) / 32, 1);                     // 1563
    const dim3 gGru(HIDDEN / 64, (N_NODES + 63) / 64);           // 4 x 782 (f0 fast)

    for (int step = 0; step < N_STEPS; ++step) {
        // k_msg reads hF16 (state written by previous k_gru / init);
        // k_gru overwrites hF16 in place (stream-serialized, safe).
        k_msg<<<gMsg, 256, 0, stream>>>(ebuf, bufA, hF16, Whi, Wlo, a);
        k_gru<<<gGru, 256, 0, stream>>>(a, hcHi, hcLo, WihH, WihL, WhhH, WhhL,
                                        b_ih, b_hh, hnHi, hnLo, hF16);
        unsigned short* t1 = hcHi; hcHi = hnHi; hnHi = t1;
        unsigned short* t2 = hcLo; hcLo = hnLo; hnLo = t2;
    }

    // ---- readout ----
    hipMemsetAsync(hg, 0, (size_t)NUM_GRAPHS * HIDDEN * 4, stream);
    k_readout1<<<(N_NODES + 31) / 32, 256, 0, stream>>>(hcHi, hcLo, gid, hg);
    k_readout2<<<NUM_GRAPHS, 256, 0, stream>>>(hg, Wc, bc, out);
}

// Round 13
// 11667.392 us; speedup vs baseline: 1.2100x; 1.2100x over previous
//
#include <hip/hip_runtime.h>
#include <math.h>

#define N_NODES   50000
#define N_EDGES   800000
#define IN_DIM    128
#define HIDDEN    256
#define N_ETYPES  13
#define N_STEPS   6
#define NUM_GRAPHS 64
#define NKEYS     (N_ETYPES * N_NODES)
#define SCAN_T    512

typedef __attribute__((ext_vector_type(8))) short bf16x8;
typedef __attribute__((ext_vector_type(4))) float f32x4;
typedef __attribute__((ext_vector_type(4))) unsigned short u16x4;
typedef __attribute__((ext_vector_type(8))) _Float16 f16x8;
typedef __attribute__((ext_vector_type(4))) _Float16 f16x4;

__device__ __forceinline__ float bf2f(unsigned short u) {
    return __uint_as_float((unsigned)u << 16);
}
__device__ __forceinline__ void fsplit(float x, unsigned short& hi, unsigned short& lo) {
    unsigned u = __float_as_uint(x);
    hi = (unsigned short)(u >> 16);
    float l = x - __uint_as_float((u >> 16) << 16);
    lo = (unsigned short)(__float_as_uint(l) >> 16);
}

// ---------------- init h0 = [feat | zeros]: bf16 hi/lo pair + f16 shadow ---
__global__ __launch_bounds__(256) void k_init_h(const float* __restrict__ feat,
                                                unsigned short* __restrict__ hHi,
                                                unsigned short* __restrict__ hLo,
                                                _Float16* __restrict__ hF16) {
    int i = blockIdx.x * 256 + threadIdx.x;          // float4 index over N*64
    if (i >= N_NODES * 64) return;
    int v = i >> 6;
    int q = i & 63;
    float4 val;
    if (q < 32) val = ((const float4*)(feat + (size_t)v * IN_DIM))[q];
    else        val = make_float4(0.f, 0.f, 0.f, 0.f);
    // fsplit cannot bind references to ext_vector elements (clang): scalars first.
    unsigned short h0, l0, h1, l1, h2, l2, h3, l3;
    fsplit(val.x, h0, l0);
    fsplit(val.y, h1, l1);
    fsplit(val.z, h2, l2);
    fsplit(val.w, h3, l3);
    u16x4 hi4, lo4;
    hi4[0] = h0; hi4[1] = h1; hi4[2] = h2; hi4[3] = h3;
    lo4[0] = l0; lo4[1] = l1; lo4[2] = l2; lo4[3] = l3;
    *(u16x4*)(hHi + (size_t)v * 256 + q * 4) = hi4;
    *(u16x4*)(hLo + (size_t)v * 256 + q * 4) = lo4;
    f16x4 f4;
    f4[0] = (_Float16)val.x; f4[1] = (_Float16)val.y;
    f4[2] = (_Float16)val.z; f4[3] = (_Float16)val.w;
    *(f16x4*)(hF16 + (size_t)v * 256 + q * 4) = f4;
}

// ---------------- split W (message) into bf16 hi/lo, transposed to [t][n][k]
__global__ __launch_bounds__(256) void k_splitW(const float* __restrict__ W,
                                                short* __restrict__ Whi,
                                                short* __restrict__ Wlo) {
    int i = blockIdx.x * 256 + threadIdx.x;          // over 13*256*256
    if (i >= N_ETYPES * 65536) return;
    int t = i >> 16, rem = i & 65535, n = rem >> 8, k = rem & 255;
    float x = W[(size_t)t * 65536 + k * 256 + n];    // W is [t][k][n]
    unsigned short hb, lb;
    fsplit(x, hb, lb);
    Whi[i] = (short)hb;                              // i == t*65536 + n*256 + k
    Wlo[i] = (short)lb;
}

// ---------------- split a linear weight [768][256] elementwise -------------
__global__ __launch_bounds__(256) void k_splitLin(const float* __restrict__ Wsrc,
                                                  short* __restrict__ hi,
                                                  short* __restrict__ lo, int n) {
    int i = blockIdx.x * 256 + threadIdx.x;
    if (i >= n) return;
    unsigned short hb, lb;
    fsplit(Wsrc[i], hb, lb);
    hi[i] = (short)hb;
    lo[i] = (short)lb;
}

// ---------------- CSR build: histogram / scan / place ----------------
__global__ __launch_bounds__(256) void k_hist(const int* __restrict__ dst,
                                              const int* __restrict__ et,
                                              int* __restrict__ counts) {
    int e = blockIdx.x * 256 + threadIdx.x;
    if (e >= N_EDGES) return;
    int key = et[e] * N_NODES + dst[e];
    atomicAdd(&counts[key], 1);
}

__global__ __launch_bounds__(SCAN_T) void k_scan1(const int* __restrict__ in,
                                                  int* __restrict__ lexcl,
                                                  int* __restrict__ bsums, int n) {
    __shared__ int s[SCAN_T];
    int i = blockIdx.x * SCAN_T + threadIdx.x;
    int v = (i < n) ? in[i] : 0;
    s[threadIdx.x] = v;
    __syncthreads();
    for (int off = 1; off < SCAN_T; off <<= 1) {
        int t = (threadIdx.x >= off) ? s[threadIdx.x - off] : 0;
        __syncthreads();
        s[threadIdx.x] += t;
        __syncthreads();
    }
    if (i < n) lexcl[i] = s[threadIdx.x] - v;
    if (threadIdx.x == SCAN_T - 1) bsums[blockIdx.x] = s[SCAN_T - 1];
}

__global__ __launch_bounds__(256) void k_scan2(int* __restrict__ bsums, int nb,
                                               int* __restrict__ ptr) {
    __shared__ int s[256];
    int tid = threadIdx.x;
    const int C = (nb + 255) / 256;                  // <= 8
    int vals[8];
    int base = tid * C;
    int sum = 0;
    for (int i = 0; i < C; ++i) {
        int idx = base + i;
        int v = (idx < nb) ? bsums[idx] : 0;
        vals[i] = sum;
        sum += v;
    }
    s[tid] = sum;
    __syncthreads();
    int own = sum;
    for (int off = 1; off < 256; off <<= 1) {
        int t = (tid >= off) ? s[tid - off] : 0;
        __syncthreads();
        s[tid] += t;
        __syncthreads();
    }
    int exclBlk = s[tid] - own;
    for (int i = 0; i < C; ++i) {
        int idx = base + i;
        if (idx < nb) bsums[idx] = exclBlk + vals[i];
    }
    if (tid == 0) ptr[NKEYS] = N_EDGES;              // end sentinel
}

__global__ __launch_bounds__(SCAN_T) void k_scan3(const int* __restrict__ lexcl,
                                                  const int* __restrict__ bsums,
                                                  int* __restrict__ ptr, int n) {
    int i = blockIdx.x * SCAN_T + threadIdx.x;
    if (i < n) ptr[i] = lexcl[i] + bsums[blockIdx.x];
}

// ebuf[pos] packs (dst<<16)|src (both < 65536); unsigned arithmetic.
__global__ __launch_bounds__(256) void k_place(const int* __restrict__ dst,
                                               const int* __restrict__ et,
                                               const int* __restrict__ src,
                                               int* __restrict__ cursor,
                                               unsigned* __restrict__ ebuf) {
    int e = blockIdx.x * 256 + threadIdx.x;
    if (e >= N_EDGES) return;
    int d = dst[e];
    int key = et[e] * N_NODES + d;
    int pos = atomicAdd(&cursor[key], 1);
    ebuf[pos] = ((unsigned)d << 16) | (unsigned)src[e];
}

// ---------------- per-etype message kernel (etype hoisted into the grid) ---
// R11 post-mortem: 13-phase in-block pipeline is the invariant bottleneck
// (occupancy x2 and bytes /2 both null). Block = (etype, 32-row tile):
// gather one bucket -> one-etype MFMA GEMM -> atomicAdd into a.
// 20K independent blocks; no cross-etype barriers; empty buckets exit early.
__device__ __forceinline__ void split8(const float4& A, const float4& B,
                                       bf16x8& hi, bf16x8& lo) {
    float x[8] = {A.x, A.y, A.z, A.w, B.x, B.y, B.z, B.w};
    #pragma unroll
    for (int e = 0; e < 8; ++e) {
        unsigned short hb, lb;
        fsplit(x[e], hb, lb);
        hi[e] = (short)hb;
        lo[e] = (short)lb;
    }
}

__global__ __launch_bounds__(256, 4) void k_msg_et(const unsigned* __restrict__ ebuf,
                                                   const int* __restrict__ ptr,
                                                   const _Float16* __restrict__ hF16,
                                                   const short* __restrict__ Whi,
                                                   const short* __restrict__ Wlo,
                                                   float* __restrict__ a) {
    __shared__ float4 Sh4[32 * 64];                  // 32 rows x 256 f32, 32 KB
    const int t    = blockIdx.x;                     // x-fast: 13 etypes of one
    const int br   = blockIdx.y * 32;                //   row tile are adjacent
    const int tid  = threadIdx.x;
    const int l    = tid & 63;
    const int w    = tid >> 6;                       // wave: cols [64w, 64w+64)
    const int ln15 = l & 15;
    const int lhi  = l >> 4;
    float* shf = (float*)Sh4;

    const int base = t * N_NODES + br;
    const int endk = (br + 32 <= N_NODES) ? (base + 32) : (t * N_NODES + N_NODES);
    const int beg  = ptr[base];
    const int end  = ptr[endk];
    if (beg == end) return;                          // empty bucket; a pre-zeroed

    // ---- zero Sh (2048 float4 / 256 threads = 8 each)
    float4 z4 = make_float4(0.f, 0.f, 0.f, 0.f);
    #pragma unroll
    for (int i = 0; i < 8; ++i) Sh4[tid + i * 256] = z4;
    __syncthreads();

    // ---- gather: wave per edge, 2-edge unroll (8 row-loads in flight/wave).
    // Lane l owns cols {l, 64+l, 128+l, 192+l}: 128B-contiguous ushort loads,
    // LDS atomic bank aliasing 2-way (free).
    for (int i = beg + w; i < end; i += 8) {
        unsigned pk1 = ebuf[i];
        int i2 = i + 4;
        int has2 = i2 < end;
        unsigned pk2 = has2 ? ebuf[i2] : pk1;
        int s1 = (int)(pk1 & 0xFFFFu), r1 = (int)(pk1 >> 16) - br;
        int s2 = (int)(pk2 & 0xFFFFu), r2 = (int)(pk2 >> 16) - br;
        float v1[4], v2[4];
        #pragma unroll
        for (int j = 0; j < 4; ++j) v1[j] = (float)hF16[(size_t)s1 * 256 + 64 * j + l];
        #pragma unroll
        for (int j = 0; j < 4; ++j) v2[j] = (float)hF16[(size_t)s2 * 256 + 64 * j + l];
        int sw1 = r1 & 7, sw2 = r2 & 7;
        #pragma unroll
        for (int j = 0; j < 4; ++j) {
            int c = 64 * j + l;
            atomicAdd(shf + r1 * 256 + (((c >> 2) ^ sw1) << 2) + (c & 3), v1[j]);
        }
        if (has2) {
            #pragma unroll
            for (int j = 0; j < 4; ++j) {
                int c = 64 * j + l;
                atomicAdd(shf + r2 * 256 + (((c >> 2) ^ sw2) << 2) + (c & 3), v2[j]);
            }
        }
    }
    __syncthreads();

    // ---- split-bf16 MFMA GEMM: Sh @ W[t][:, 64w..64w+64)
    f32x4 acc[2][4] = {};                            // [row-frag][col-frag]
    const short* WH = Whi + ((size_t)t << 16);
    const short* WL = Wlo + ((size_t)t << 16);
    #pragma unroll 2
    for (int K0 = 0; K0 < 8; ++K0) {                 // K = K0*32
        bf16x8 bh[4], bl[4];
        #pragma unroll
        for (int cb = 0; cb < 4; ++cb) {
            int col = (w << 6) + (cb << 4) + ln15;
            size_t off = (size_t)col * 256 + (K0 << 5) + (lhi << 3);
            bh[cb] = *reinterpret_cast<const bf16x8*>(WH + off);
            bl[cb] = *reinterpret_cast<const bf16x8*>(WL + off);
        }
        #pragma unroll
        for (int rf = 0; rf < 2; ++rf) {
            int row = (rf << 4) + ln15;
            int j0  = (K0 << 3) + (lhi << 1);
            int sw  = row & 7;
            float4 a0 = Sh4[row * 64 + (j0 ^ sw)];
            float4 a1 = Sh4[row * 64 + ((j0 + 1) ^ sw)];
            bf16x8 ah, al;
            split8(a0, a1, ah, al);
            #pragma unroll
            for (int cb = 0; cb < 4; ++cb) {
                acc[rf][cb] = __builtin_amdgcn_mfma_f32_16x16x32_bf16(ah, bh[cb], acc[rf][cb], 0, 0, 0);
                acc[rf][cb] = __builtin_amdgcn_mfma_f32_16x16x32_bf16(ah, bl[cb], acc[rf][cb], 0, 0, 0);
                acc[rf][cb] = __builtin_amdgcn_mfma_f32_16x16x32_bf16(al, bh[cb], acc[rf][cb], 0, 0, 0);
            }
        }
    }
    // ---- accumulate into a (device-scope f32 atomics; a pre-zeroed per step)
    #pragma unroll
    for (int rf = 0; rf < 2; ++rf) {
        #pragma unroll
        for (int m = 0; m < 4; ++m) {
            int row = br + (rf << 4) + (lhi << 2) + m;
            if (row < N_NODES) {
                #pragma unroll
                for (int cb = 0; cb < 4; ++cb) {
                    int col = (w << 6) + (cb << 4) + ln15;
                    atomicAdd(a + (size_t)row * 256 + col, acc[rf][cb][m]);
                }
            }
        }
    }
}

// ---------------- MFMA GRU kernel (h state = bf16 hi/lo; writes f16 shadow)
__device__ __forceinline__ float sigm(float x) { return 1.0f / (1.0f + expf(-x)); }

__global__ __launch_bounds__(256, 2) void k_gru(const float* __restrict__ a,
                                                const unsigned short* __restrict__ hHi,
                                                const unsigned short* __restrict__ hLo,
                                                const short* __restrict__ WihH,
                                                const short* __restrict__ WihL,
                                                const short* __restrict__ WhhH,
                                                const short* __restrict__ WhhL,
                                                const float* __restrict__ b_ih,
                                                const float* __restrict__ b_hh,
                                                unsigned short* __restrict__ hNHi,
                                                unsigned short* __restrict__ hNLo,
                                                _Float16* __restrict__ hNF16) {
    const int f0   = blockIdx.x * 64;                // x-fast: f0 varies first
    const int br   = blockIdx.y * 64;
    const int tid  = threadIdx.x;
    const int w    = tid >> 6;
    const int l    = tid & 63;
    const int ln15 = l & 15;
    const int lhi  = l >> 4;

    f32x4 accx[3][4] = {};                           // [gate][col-frag]
    f32x4 acch[3][4] = {};

    int rowA = br + (w << 4) + ln15;                 // A-frag row for this lane
    if (rowA >= N_NODES) rowA = N_NODES - 1;         // clamp, stores guarded
    const float* aRow = a + (size_t)rowA * 256;
    const unsigned short* hHiRow = hHi + (size_t)rowA * 256;
    const unsigned short* hLoRow = hLo + (size_t)rowA * 256;

    #pragma unroll 2
    for (int K0 = 0; K0 < 8; ++K0) {
        const int koff = (K0 << 5) + (lhi << 3);
        float4 av0 = *(const float4*)(aRow + koff);
        float4 av1 = *(const float4*)(aRow + koff + 4);
        bf16x8 aH, aL;
        split8(av0, av1, aH, aL);
        bf16x8 hH = *reinterpret_cast<const bf16x8*>(hHiRow + koff);
        bf16x8 hL = *reinterpret_cast<const bf16x8*>(hLoRow + koff);
        #pragma unroll
        for (int g = 0; g < 3; ++g) {
            #pragma unroll
            for (int cb = 0; cb < 4; ++cb) {
                int col = g * 256 + f0 + (cb << 4) + ln15;
                size_t off = (size_t)col * 256 + koff;
                bf16x8 bH = *reinterpret_cast<const bf16x8*>(WihH + off);
                bf16x8 bL = *reinterpret_cast<const bf16x8*>(WihL + off);
                accx[g][cb] = __builtin_amdgcn_mfma_f32_16x16x32_bf16(aH, bH, accx[g][cb], 0, 0, 0);
                accx[g][cb] = __builtin_amdgcn_mfma_f32_16x16x32_bf16(aH, bL, accx[g][cb], 0, 0, 0);
                accx[g][cb] = __builtin_amdgcn_mfma_f32_16x16x32_bf16(aL, bH, accx[g][cb], 0, 0, 0);
                bH = *reinterpret_cast<const bf16x8*>(WhhH + off);
                bL = *reinterpret_cast<const bf16x8*>(WhhL + off);
                acch[g][cb] = __builtin_amdgcn_mfma_f32_16x16x32_bf16(hH, bH, acch[g][cb], 0, 0, 0);
                acch[g][cb] = __builtin_amdgcn_mfma_f32_16x16x32_bf16(hH, bL, acch[g][cb], 0, 0, 0);
                acch[g][cb] = __builtin_amdgcn_mfma_f32_16x16x32_bf16(hL, bH, acch[g][cb], 0, 0, 0);
            }
        }
    }
    // ---- gate epilogue; C/D frag: col = 16cb+ln15, row = 16w + 4*lhi + m
    #pragma unroll
    for (int cb = 0; cb < 4; ++cb) {
        int f = f0 + (cb << 4) + ln15;
        float bxr = b_ih[f], bxz = b_ih[256 + f], bxn = b_ih[512 + f];
        float bhr = b_hh[f], bhz = b_hh[256 + f], bhn = b_hh[512 + f];
        #pragma unroll
        for (int m = 0; m < 4; ++m) {
            int row = br + (w << 4) + (lhi << 2) + m;
            if (row >= N_NODES) continue;
            size_t idx = (size_t)row * 256 + f;
            float hv = bf2f(hHi[idx]) + bf2f(hLo[idx]);
            float r = sigm(accx[0][cb][m] + bxr + acch[0][cb][m] + bhr);
            float z = sigm(accx[1][cb][m] + bxz + acch[1][cb][m] + bhz);
            float n = tanhf(accx[2][cb][m] + bxn + r * (acch[2][cb][m] + bhn));
            float o = (1.f - z) * n + z * hv;
            unsigned short ohi, olo;
            fsplit(o, ohi, olo);
            hNHi[idx] = ohi;
            hNLo[idx] = olo;
            hNF16[idx] = (_Float16)o;
        }
    }
}

// ---------------- readout ----------------
__global__ __launch_bounds__(256) void k_readout1(const unsigned short* __restrict__ hHi,
                                                  const unsigned short* __restrict__ hLo,
                                                  const int* __restrict__ gid,
                                                  float* __restrict__ hg) {
    int row0 = blockIdx.x * 32;
    if (row0 >= N_NODES) return;
    int f = threadIdx.x;
    int end = row0 + 32; if (end > N_NODES) end = N_NODES;
    float acc = 0.f;
    int cur = gid[row0];
    for (int r = row0; r < end; ++r) {
        int g = gid[r];
        if (g != cur) {
            atomicAdd(&hg[cur * HIDDEN + f], acc);
            acc = 0.f; cur = g;
        }
        size_t idx = (size_t)r * HIDDEN + f;
        float x = bf2f(hHi[idx]) + bf2f(hLo[idx]);
        acc += (x > 0.f) ? x : 0.f;
    }
    atomicAdd(&hg[cur * HIDDEN + f], acc);
}

__global__ __launch_bounds__(256) void k_readout2(const float* __restrict__ hg,
                                                  const float* __restrict__ Wc,
                                                  const float* __restrict__ bc,
                                                  float* __restrict__ out) {
    __shared__ float s[256];
    int g = blockIdx.x;
    int f = threadIdx.x;
    s[f] = hg[g * HIDDEN + f] * Wc[f];
    __syncthreads();
    for (int off = 128; off > 0; off >>= 1) {
        if (f < off) s[f] += s[f + off];
        __syncthreads();
    }
    if (f == 0) out[g] = 1.0f / (1.0f + expf(-(s[0] + bc[0])));
}

// ---------------- launch ----------------
extern "C" void kernel_launch(void* const* d_in, const int* in_sizes, int n_in,
                              void* d_out, int out_size, void* d_ws, size_t ws_size,
                              hipStream_t stream) {
    const float* feat  = (const float*)d_in[0];
    const float* W     = (const float*)d_in[1];
    const float* W_ih  = (const float*)d_in[2];
    const float* W_hh  = (const float*)d_in[3];
    const float* b_ih  = (const float*)d_in[4];
    const float* b_hh  = (const float*)d_in[5];
    const float* Wc    = (const float*)d_in[6];
    const float* bc    = (const float*)d_in[7];
    const int*   src   = (const int*)d_in[8];
    const int*   dst   = (const int*)d_in[9];
    const int*   etype = (const int*)d_in[10];
    const int*   gid   = (const int*)d_in[11];
    float* out = (float*)d_out;

    char* ws = (char*)d_ws;
    size_t off = 0;
    auto alloc = [&](size_t bytes) {
        void* p = ws + off;
        off += (bytes + 255) & ~(size_t)255;
        return p;
    };
    // total ~193 MB
    unsigned short* hHiA = (unsigned short*)alloc((size_t)N_NODES * HIDDEN * 2); // 25.6 MB
    unsigned short* hLoA = (unsigned short*)alloc((size_t)N_NODES * HIDDEN * 2);
    unsigned short* hHiB = (unsigned short*)alloc((size_t)N_NODES * HIDDEN * 2);
    unsigned short* hLoB = (unsigned short*)alloc((size_t)N_NODES * HIDDEN * 2);
    _Float16* hF16 = (_Float16*)alloc((size_t)N_NODES * HIDDEN * 2);             // 25.6 MB, single buffer
    float* a    = (float*)alloc((size_t)N_NODES * HIDDEN * 4);   // 51.2 MB
    int* bufA   = (int*)alloc((size_t)(NKEYS + 1) * 4);          // counts, then ptr
    int* bufB   = (int*)alloc((size_t)NKEYS * 4);                // lexcl, then cursor
    unsigned* ebuf = (unsigned*)alloc((size_t)N_EDGES * 4);      // (dst<<16)|src
    int* bsums  = (int*)alloc((size_t)2048 * 4);
    float* hg   = (float*)alloc((size_t)NUM_GRAPHS * HIDDEN * 4);
    short* Whi  = (short*)alloc((size_t)N_ETYPES * 65536 * 2);   // 1.7 MB
    short* Wlo  = (short*)alloc((size_t)N_ETYPES * 65536 * 2);   // 1.7 MB
    short* WihH = (short*)alloc((size_t)768 * 256 * 2);          // 393 KB
    short* WihL = (short*)alloc((size_t)768 * 256 * 2);
    short* WhhH = (short*)alloc((size_t)768 * 256 * 2);
    short* WhhL = (short*)alloc((size_t)768 * 256 * 2);
    (void)ws_size; (void)n_in; (void)in_sizes; (void)out_size;

    const int SCAN_BLOCKS = (NKEYS + SCAN_T - 1) / SCAN_T;       // 1270
    const int NLIN = 768 * 256;

    // ---- CSR build, bucketed by (etype, dst) ----
    hipMemsetAsync(bufA, 0, (size_t)NKEYS * 4, stream);
    k_hist<<<(N_EDGES + 255) / 256, 256, 0, stream>>>(dst, etype, bufA);
    k_scan1<<<SCAN_BLOCKS, SCAN_T, 0, stream>>>(bufA, bufB, bsums, NKEYS);
    k_scan2<<<1, 256, 0, stream>>>(bsums, SCAN_BLOCKS, bufA);
    k_scan3<<<SCAN_BLOCKS, SCAN_T, 0, stream>>>(bufB, bsums, bufA, NKEYS);
    hipMemcpyAsync(bufB, bufA, (size_t)NKEYS * 4, hipMemcpyDeviceToDevice, stream);
    k_place<<<(N_EDGES + 255) / 256, 256, 0, stream>>>(dst, etype, src, bufB, ebuf);

    // ---- weight splits (once) + h0 ----
    k_splitW<<<(N_ETYPES * 65536 + 255) / 256, 256, 0, stream>>>(W, Whi, Wlo);
    k_splitLin<<<(NLIN + 255) / 256, 256, 0, stream>>>(W_ih, WihH, WihL, NLIN);
    k_splitLin<<<(NLIN + 255) / 256, 256, 0, stream>>>(W_hh, WhhH, WhhL, NLIN);
    k_init_h<<<(N_NODES * 64 + 255) / 256, 256, 0, stream>>>(feat, hHiA, hLoA, hF16);

    unsigned short* hcHi = hHiA; unsigned short* hcLo = hLoA;
    unsigned short* hnHi = hHiB; unsigned short* hnLo = hLoB;
    const dim3 gMsg(N_ETYPES, (N_NODES + 31) / 32);              // 13 x 1563, t fast
    const dim3 gGru(HIDDEN / 64, (N_NODES + 63) / 64);           // 4 x 782 (f0 fast)

    for (int step = 0; step < N_STEPS; ++step) {
        hipMemsetAsync(a, 0, (size_t)N_NODES * HIDDEN * 4, stream);
        // k_msg_et reads hF16 (written by previous k_gru / init);
        // k_gru overwrites hF16 in place (stream-serialized, safe).
        k_msg_et<<<gMsg, 256, 0, stream>>>(ebuf, bufA, hF16, Whi, Wlo, a);
        k_gru<<<gGru, 256, 0, stream>>>(a, hcHi, hcLo, WihH, WihL, WhhH, WhhL,
                                        b_ih, b_hh, hnHi, hnLo, hF16);
        unsigned short* t1 = hcHi; hcHi = hnHi; hnHi = t1;
        unsigned short* t2 = hcLo; hcLo = hnLo; hnLo = t2;
    }

    // ---- readout ----
    hipMemsetAsync(hg, 0, (size_t)NUM_GRAPHS * HIDDEN * 4, stream);
    k_readout1<<<(N_NODES + 31) / 32, 256, 0, stream>>>(hcHi, hcLo, gid, hg);
    k_readout2<<<NUM_GRAPHS, 256, 0, stream>>>(hg, Wc, bc, out);
}